// Round 9
// baseline (169.270 us; speedup 1.0000x reference)
//
#include <hip/hip_runtime.h>
#include <hip/hip_bf16.h>

typedef __attribute__((ext_vector_type(8))) short short8;
typedef __attribute__((ext_vector_type(4))) float f32x4;
typedef unsigned short ushort;

// ---------------- gamma = mean(|W|) + 1e-6, deterministic two-stage ----------------

__global__ void kabs_partial(const float* __restrict__ W, double* __restrict__ part, int n) {
    __shared__ double sd[256];
    const int tid = threadIdx.x;
    double s = 0.0;
    for (int i = blockIdx.x * blockDim.x + tid; i < n; i += gridDim.x * blockDim.x)
        s += (double)fabsf(W[i]);
    sd[tid] = s;
    __syncthreads();
    for (int off = 128; off > 0; off >>= 1) {
        if (tid < off) sd[tid] += sd[tid + off];
        __syncthreads();
    }
    if (tid == 0) part[blockIdx.x] = sd[0];
}

__global__ void kgamma(const double* __restrict__ part, float* __restrict__ gout, int nelem) {
    __shared__ double sd[256];
    const int tid = threadIdx.x;
    double s = part[tid] + part[tid + 256] + part[tid + 512] + part[tid + 768];
    sd[tid] = s;
    __syncthreads();
    for (int off = 128; off > 0; off >>= 1) {
        if (tid < off) sd[tid] += sd[tid + off];
        __syncthreads();
    }
    if (tid == 0) gout[0] = (float)(sd[0] / (double)nelem) + 1e-6f;
}

// ---------------- quantizers: write bf16 {-1,0,+1} bit patterns ----------------

__device__ __forceinline__ unsigned int qw_h(float w, float g) {
    float t = fabsf(w) / g;
    unsigned int u = __float_as_uint(w);
    unsigned int h = 0x3F80u | ((u >> 16) & 0x8000u);   // +-1.0 bf16
    return (rintf(t) >= 1.0f) ? h : 0u;
}

__global__ void kquant_w(const float4* __restrict__ W4, unsigned short* __restrict__ Wq,
                         const float* __restrict__ gptr, int n4) {
    int i = blockIdx.x * blockDim.x + threadIdx.x;
    if (i >= n4) return;
    const float g = *gptr;
    float4 w = W4[i];
    unsigned int h0 = qw_h(w.x, g) | (qw_h(w.y, g) << 16);
    unsigned int h1 = qw_h(w.z, g) | (qw_h(w.w, g) << 16);
    ((uint2*)Wq)[i] = make_uint2(h0, h1);
}

__device__ __forceinline__ unsigned int sgn_h(float a) {
    unsigned int u = __float_as_uint(a);
    return (u & 0x7FFFFFFFu) ? (0x3F80u | ((u >> 16) & 0x8000u)) : 0u;
}
__device__ __forceinline__ unsigned int sgn2(float a, float b) {
    return sgn_h(a) | (sgn_h(b) << 16);
}

__global__ void kquant_x(const float4* __restrict__ X4, uint4* __restrict__ Xq, size_t n8) {
    size_t i = (size_t)blockIdx.x * blockDim.x + threadIdx.x;
    if (i >= n8) return;
    float4 a = X4[2 * i], b = X4[2 * i + 1];
    uint4 o;
    o.x = sgn2(a.x, a.y);
    o.y = sgn2(a.z, a.w);
    o.z = sgn2(b.x, b.y);
    o.w = sgn2(b.z, b.w);
    Xq[i] = o;
}

// ---------------- 256x256 8-phase bf16 MFMA GEMM, ONE barrier/phase ----------------
// C[M][N] = A[M][K] * B[N][K]^T. 8 waves (2M x 4N), per-wave 128x64 output.
// Tile tau lives in buf tau&1. Phase p = {STAGE(calendar p); [vmcnt(6) @ph4/ph8];
// BARRIER; lgkmcnt(0)+sched_barrier; setprio(1); [16 MFMA (ks-outer) || ds_reads for
// p+1, interleaved via sched_group_barrier DS/MFMA pattern]; setprio(0)}.
// The SGB interleave keeps LDS pipe and matrix pipe busy simultaneously (the R8
// profile showed them serialized: 620cyc MFMA + ~400cyc reads + ~100 barrier = 1100).
// Safety: calendar/ledger identical to R8 (verified absmax=0): stage-into-region q >=
// last-read r + 1; certify vmcnt(6) at ph4/ph8 drains exactly one full tile, >=3
// phases slack; tail clamps re-stage identical data into dead regions.

#define STAGE_HALF(SRC, DST, BASE_ROW, KB)                                                  \
    {                                                                                       \
        _Pragma("unroll")                                                                   \
        for (int l = 0; l < 2; ++l) {                                                       \
            const int r_ = l * 64 + srow;                                                   \
            const ushort* g_ = (SRC) + (size_t)((BASE_ROW) + r_) * K + (KB) +               \
                               (sec ^ ((r_ & 7) << 3));                                     \
            __builtin_amdgcn_global_load_lds(                                               \
                (const __attribute__((address_space(1))) unsigned int*)g_,                  \
                (__attribute__((address_space(3))) unsigned int*)&(DST)[r_][sec], 16, 0, 0);\
        }                                                                                   \
    }

#define BARRIER do { asm volatile("" ::: "memory"); __builtin_amdgcn_s_barrier(); \
                     asm volatile("" ::: "memory"); } while (0)
#define LGKM0   do { asm volatile("s_waitcnt lgkmcnt(0)" ::: "memory"); \
                     __builtin_amdgcn_sched_barrier(0); } while (0)
#define VMC6    asm volatile("s_waitcnt vmcnt(6)" ::: "memory")

#define DS_READ_A(BUF, m, dst)                                                              \
    {                                                                                       \
        const int ra = wm * 64 + ((m) & 3) * 16 + lr;                                       \
        _Pragma("unroll")                                                                   \
        for (int ks = 0; ks < 2; ++ks)                                                      \
            dst[ks] = *(const short8*)&As[BUF][(m) >> 2][ra][(ks * 32 + lk) ^ ((ra & 7) << 3)]; \
    }

#define DS_READ_B(BUF)                                                                      \
    {                                                                                       \
        _Pragma("unroll")                                                                   \
        for (int n = 0; n < 4; ++n) {                                                       \
            const int rb = (wn & 1) * 64 + n * 16 + lr;                                     \
            _Pragma("unroll")                                                               \
            for (int ks = 0; ks < 2; ++ks)                                                  \
                bv[n][ks] = *(const short8*)&Bs[BUF][wn >> 1][rb][(ks * 32 + lk) ^ ((rb & 7) << 3)]; \
        }                                                                                   \
    }

// ks OUTER: 8 independent MFMAs between each dependent (same-acc) pair
#define MFMA_BODY(mb, AV)                                                                   \
    {                                                                                       \
        _Pragma("unroll")                                                                   \
        for (int ks = 0; ks < 2; ++ks)                                                      \
            _Pragma("unroll")                                                               \
            for (int mi = 0; mi < 2; ++mi)                                                  \
                _Pragma("unroll")                                                           \
                for (int n = 0; n < 4; ++n)                                                 \
                    acc[(mb) + mi][n] = __builtin_amdgcn_mfma_f32_16x16x32_bf16(            \
                        AV[mi][ks], bv[n][ks], acc[(mb) + mi][n], 0, 0, 0);                 \
    }

// sched_group_barrier masks: MFMA=0x8, DS_READ=0x100
#define SGB_REG                                                                             \
    {                                                                                       \
        _Pragma("unroll")                                                                   \
        for (int g_ = 0; g_ < 4; ++g_) {                                                    \
            __builtin_amdgcn_sched_group_barrier(0x100, 1, 0);                              \
            __builtin_amdgcn_sched_group_barrier(0x008, 4, 0);                              \
        }                                                                                   \
    }
#define SGB_HEAVY                                                                           \
    {                                                                                       \
        _Pragma("unroll")                                                                   \
        for (int g_ = 0; g_ < 4; ++g_) {                                                    \
            __builtin_amdgcn_sched_group_barrier(0x100, 3, 0);                              \
            __builtin_amdgcn_sched_group_barrier(0x008, 4, 0);                              \
        }                                                                                   \
    }

__global__ __launch_bounds__(512, 2) void kgemm(const ushort* __restrict__ A,
                                                const ushort* __restrict__ B,
                                                float* __restrict__ C,
                                                int M, int N, int K) {
    __shared__ ushort As[2][2][128][64];
    __shared__ ushort Bs[2][2][128][64];

    const int tid = threadIdx.x;
    const int lane = tid & 63;
    const int wid = tid >> 6;      // 0..7
    const int wm = wid >> 2;       // 0..1  (M sub-block within each half)
    const int wn = wid & 3;        // 0..3  (N sub-block)

    // T1: XCD-aware block swizzle (grid % 8 == 0 here)
    int bid = blockIdx.x;
    const int nwg = gridDim.x;
    if ((nwg & 7) == 0) bid = (bid & 7) * (nwg >> 3) + (bid >> 3);
    const int nbn = N >> 8;
    const int bm = bid / nbn, bn = bid % nbn;
    const int row0 = bm << 8, col0 = bn << 8;

    const int lr = lane & 15;
    const int lk = (lane >> 4) * 8;

    // staging thread mapping: 512 threads cover 64 rows x 64 cols per load instr
    const int srow = tid >> 3;          // 0..63
    const int sec  = (tid & 7) * 8;     // element chunk (8 bf16 = 16 B)

    f32x4 acc[8][4] = {};
    const int NT = K >> 6;              // even (K % 128 == 0 guaranteed by launcher)

    // ---- prologue: tile0 (4 halves) + tile1 (3 halves); certify tile0; preload ph1 frags
    STAGE_HALF(B, Bs[0][0], col0, 0);
    STAGE_HALF(B, Bs[0][1], col0 + 128, 0);
    STAGE_HALF(A, As[0][0], row0, 0);
    STAGE_HALF(A, As[0][1], row0 + 128, 0);
    STAGE_HALF(B, Bs[1][0], col0, 64);
    STAGE_HALF(B, Bs[1][1], col0 + 128, 64);
    STAGE_HALF(A, As[1][0], row0, 64);
    VMC6;
    BARRIER;

    short8 bv[4][2], av0[2][2], av1[2][2];
    DS_READ_B(0);
    DS_READ_A(0, 0, av0[0]); DS_READ_A(0, 1, av0[1]);

    for (int t = 0; t < NT; t += 2) {
        const int kb1 = (t + 1) << 6;
        const int kb2 = (t + 2 < NT ? t + 2 : NT - 1) << 6;   // clamped tail: dead-region
        const int kb3 = (t + 3 < NT ? t + 3 : NT - 1) << 6;   // re-stage, ledger exact

        // ph1: MFMA m0-1 (tile t) || read m2-3
        STAGE_HALF(A, As[1][1], row0 + 128, kb1);
        BARRIER; LGKM0;
        __builtin_amdgcn_s_setprio(1);
        MFMA_BODY(0, av0);
        DS_READ_A(0, 2, av1[0]); DS_READ_A(0, 3, av1[1]);
        SGB_REG;
        __builtin_amdgcn_s_setprio(0);
        // ph2: MFMA m2-3 || read m4-5
        STAGE_HALF(B, Bs[0][0], col0, kb2);
        BARRIER; LGKM0;
        __builtin_amdgcn_s_setprio(1);
        MFMA_BODY(2, av1);
        DS_READ_A(0, 4, av0[0]); DS_READ_A(0, 5, av0[1]);
        SGB_REG;
        __builtin_amdgcn_s_setprio(0);
        // ph3: MFMA m4-5 || read m6-7
        STAGE_HALF(B, Bs[0][1], col0 + 128, kb2);
        BARRIER; LGKM0;
        __builtin_amdgcn_s_setprio(1);
        MFMA_BODY(4, av0);
        DS_READ_A(0, 6, av1[0]); DS_READ_A(0, 7, av1[1]);
        SGB_REG;
        __builtin_amdgcn_s_setprio(0);
        // ph4: certify tile t+1; MFMA m6-7 || read tile t+1 B + m0-1
        STAGE_HALF(A, As[0][0], row0, kb2);
        VMC6;
        BARRIER; LGKM0;
        __builtin_amdgcn_s_setprio(1);
        MFMA_BODY(6, av1);
        DS_READ_B(1);
        DS_READ_A(1, 0, av0[0]); DS_READ_A(1, 1, av0[1]);
        SGB_HEAVY;
        __builtin_amdgcn_s_setprio(0);
        // ph5: MFMA m0-1 (tile t+1) || read m2-3
        STAGE_HALF(A, As[0][1], row0 + 128, kb2);
        BARRIER; LGKM0;
        __builtin_amdgcn_s_setprio(1);
        MFMA_BODY(0, av0);
        DS_READ_A(1, 2, av1[0]); DS_READ_A(1, 3, av1[1]);
        SGB_REG;
        __builtin_amdgcn_s_setprio(0);
        // ph6: MFMA m2-3 || read m4-5
        STAGE_HALF(B, Bs[1][0], col0, kb3);
        BARRIER; LGKM0;
        __builtin_amdgcn_s_setprio(1);
        MFMA_BODY(2, av1);
        DS_READ_A(1, 4, av0[0]); DS_READ_A(1, 5, av0[1]);
        SGB_REG;
        __builtin_amdgcn_s_setprio(0);
        // ph7: MFMA m4-5 || read m6-7
        STAGE_HALF(B, Bs[1][1], col0 + 128, kb3);
        BARRIER; LGKM0;
        __builtin_amdgcn_s_setprio(1);
        MFMA_BODY(4, av0);
        DS_READ_A(1, 6, av1[0]); DS_READ_A(1, 7, av1[1]);
        SGB_REG;
        __builtin_amdgcn_s_setprio(0);
        // ph8: certify tile t+2; MFMA m6-7 || read tile t+2 B + m0-1
        STAGE_HALF(A, As[1][0], row0, kb3);
        VMC6;
        BARRIER; LGKM0;
        __builtin_amdgcn_s_setprio(1);
        MFMA_BODY(6, av1);
        DS_READ_B(0);
        DS_READ_A(0, 0, av0[0]); DS_READ_A(0, 1, av0[1]);
        SGB_HEAVY;
        __builtin_amdgcn_s_setprio(0);
    }
    asm volatile("s_waitcnt vmcnt(0) lgkmcnt(0)" ::: "memory");

    // ---- epilogue: C/D layout col = lane&15, row = (lane>>4)*4 + reg (m89-verified)
#pragma unroll
    for (int m = 0; m < 8; ++m) {
        const int grow = row0 + (m >> 2) * 128 + wm * 64 + (m & 3) * 16 + (lane >> 4) * 4;
#pragma unroll
        for (int n = 0; n < 4; ++n) {
            float* cp = C + (size_t)grow * N + col0 + wn * 64 + n * 16 + (lane & 15);
#pragma unroll
            for (int r = 0; r < 4; ++r)
                cp[(size_t)r * N] = acc[m][n][r];
        }
    }
}

// ---------------- correct-but-slow fallback if workspace is tiny ----------------

__global__ void knaive(const float* __restrict__ X, const float* __restrict__ W,
                       const float* __restrict__ gptr, float* __restrict__ out,
                       int N, int K) {
    size_t idx = (size_t)blockIdx.x * blockDim.x + threadIdx.x;
    const int m = (int)(idx / N), n = (int)(idx % N);
    const float g = *gptr;
    const float* xr = X + (size_t)m * K;
    const float* wrow = W + (size_t)n * K;
    float acc = 0.f;
    for (int k = 0; k < K; ++k) {
        float xv = xr[k];
        float xs = (xv > 0.f) ? 1.f : ((xv < 0.f) ? -1.f : 0.f);
        float w = wrow[k];
        float wq = (rintf(fabsf(w) / g) >= 1.f) ? ((w < 0.f) ? -1.f : 1.f) : 0.f;
        acc += xs * wq;
    }
    out[idx] = acc;
}

// ---------------- launch ----------------

extern "C" void kernel_launch(void* const* d_in, const int* in_sizes, int n_in,
                              void* d_out, int out_size, void* d_ws, size_t ws_size,
                              hipStream_t stream) {
    const float* x = (const float*)d_in[0];
    const float* W = (const float*)d_in[1];
    float* out = (float*)d_out;

    const int K = 2048;                 // in_features
    const int N = in_sizes[1] / K;      // out_features = 2048
    const int M = in_sizes[0] / K;      // 4*4096 = 16384
    const int nW = in_sizes[1];

    char* ws = (char*)d_ws;
    double* partials = (double*)ws;                       // 1024 doubles = 8 KB
    float* gamma = (float*)(ws + 8192);
    ushort* wq = (ushort*)(ws + 16384);
    ushort* xq = (ushort*)(ws + 16384 + (size_t)N * K * 2);
    const size_t need = 16384 + (size_t)N * K * 2 + (size_t)M * K * 2;

    kabs_partial<<<1024, 256, 0, stream>>>(W, partials, nW);
    kgamma<<<1, 256, 0, stream>>>(partials, gamma, nW);

    if (ws_size >= need && (M % 256) == 0 && (N % 256) == 0 && (K % 128) == 0) {
        kquant_w<<<nW / (256 * 4), 256, 0, stream>>>((const float4*)W, wq, gamma, nW / 4);
        const size_t n8 = (size_t)M * K / 8;
        kquant_x<<<(unsigned)(n8 / 256), 256, 0, stream>>>((const float4*)x, (uint4*)xq, n8);
        kgemm<<<(M / 256) * (N / 256), 512, 0, stream>>>(xq, wq, out, M, N, K);
    } else {
        knaive<<<(unsigned)((size_t)M * N / 256), 256, 0, stream>>>(x, W, gamma, out, N, K);
    }
}

// Round 10
// 124.981 us; speedup vs baseline: 1.3544x; 1.3544x over previous
//
#include <hip/hip_runtime.h>
#include <hip/hip_bf16.h>

typedef __attribute__((ext_vector_type(4))) int i32x4;
typedef unsigned char u8;

// ---------------- gamma = mean(|W|) + 1e-6, deterministic two-stage ----------------

__global__ void kabs_partial(const float* __restrict__ W, double* __restrict__ part, int n) {
    __shared__ double sd[256];
    const int tid = threadIdx.x;
    double s = 0.0;
    for (int i = blockIdx.x * blockDim.x + tid; i < n; i += gridDim.x * blockDim.x)
        s += (double)fabsf(W[i]);
    sd[tid] = s;
    __syncthreads();
    for (int off = 128; off > 0; off >>= 1) {
        if (tid < off) sd[tid] += sd[tid + off];
        __syncthreads();
    }
    if (tid == 0) part[blockIdx.x] = sd[0];
}

__global__ void kgamma(const double* __restrict__ part, float* __restrict__ gout, int nelem) {
    __shared__ double sd[256];
    const int tid = threadIdx.x;
    double s = part[tid] + part[tid + 256] + part[tid + 512] + part[tid + 768];
    sd[tid] = s;
    __syncthreads();
    for (int off = 128; off > 0; off >>= 1) {
        if (tid < off) sd[tid] += sd[tid + off];
        __syncthreads();
    }
    if (tid == 0) gout[0] = (float)(sd[0] / (double)nelem) + 1e-6f;
}

// ---------------- quantizers: write i8 {-1,0,+1} ----------------

__device__ __forceinline__ unsigned int qw_b(float w, float g) {
    float t = fabsf(w) / g;
    unsigned int u = __float_as_uint(w);
    return (rintf(t) >= 1.0f) ? ((u >> 31) ? 0xFFu : 0x01u) : 0u;
}

__global__ void kquant_w(const float4* __restrict__ W4, unsigned int* __restrict__ Wq,
                         const float* __restrict__ gptr, int n4) {
    int i = blockIdx.x * blockDim.x + threadIdx.x;
    if (i >= n4) return;
    const float g = *gptr;
    float4 w = W4[i];
    Wq[i] = qw_b(w.x, g) | (qw_b(w.y, g) << 8) | (qw_b(w.z, g) << 16) | (qw_b(w.w, g) << 24);
}

__device__ __forceinline__ unsigned int sgn_b(float a) {
    unsigned int u = __float_as_uint(a);
    return (u & 0x7FFFFFFFu) ? ((u >> 31) ? 0xFFu : 0x01u) : 0u;
}
__device__ __forceinline__ unsigned int sgn4(float4 v) {
    return sgn_b(v.x) | (sgn_b(v.y) << 8) | (sgn_b(v.z) << 16) | (sgn_b(v.w) << 24);
}

__global__ void kquant_x(const float4* __restrict__ X4, uint4* __restrict__ Xq, size_t n16) {
    size_t i = (size_t)blockIdx.x * blockDim.x + threadIdx.x;
    if (i >= n16) return;
    uint4 o;
    o.x = sgn4(X4[4 * i]);
    o.y = sgn4(X4[4 * i + 1]);
    o.z = sgn4(X4[4 * i + 2]);
    o.w = sgn4(X4[4 * i + 3]);
    Xq[i] = o;
}

// ---------------- 256x256 8-phase i8 MFMA GEMM, ONE barrier/phase ----------------
// C[M][N] = A[M][K] * B[N][K]^T, A/B i8 {-1,0,+1}, acc i32 (exact), out f32.
// Byte-identical schedule to the verified R8 bf16 kernel: 8 waves (2M x 4N), per-wave
// 128x64 output; tile tau (K=128 i8 = 128B rows, same as 64 bf16) in buf tau&1;
// phase p = {STAGE(calendar); [vmcnt(6)@ph4/ph8]; BARRIER; lgkm0+sched_barrier;
// setprio(1); 16x mfma_i32_16x16x64_i8 on frags read at p-1; setprio(0); ds_read p+1}.
// Same stage calendar, same vmcnt ledger (2 loads/phase, certify drains exactly one
// full tile with >=3 phases slack), same XOR-16B swizzle. K per tile doubles -> phase
// count halves vs bf16 at equal per-phase cost: the 2x-rate i8 pipe is the win.

#define STAGE_HALF(SRC, DST, BASE_ROW, KB)                                                  \
    {                                                                                       \
        _Pragma("unroll")                                                                   \
        for (int l = 0; l < 2; ++l) {                                                       \
            const int r_ = l * 64 + srow;                                                   \
            const u8* g_ = (SRC) + (size_t)((BASE_ROW) + r_) * K + (KB) +                   \
                           (sec ^ ((r_ & 7) << 4));                                         \
            __builtin_amdgcn_global_load_lds(                                               \
                (const __attribute__((address_space(1))) unsigned int*)g_,                  \
                (__attribute__((address_space(3))) unsigned int*)&(DST)[r_][sec], 16, 0, 0);\
        }                                                                                   \
    }

#define BARRIER do { asm volatile("" ::: "memory"); __builtin_amdgcn_s_barrier(); \
                     asm volatile("" ::: "memory"); } while (0)
#define LGKM0   do { asm volatile("s_waitcnt lgkmcnt(0)" ::: "memory"); \
                     __builtin_amdgcn_sched_barrier(0); } while (0)
#define VMC6    asm volatile("s_waitcnt vmcnt(6)" ::: "memory")

#define DS_READ_A(BUF, m, dst)                                                              \
    {                                                                                       \
        const int ra = wm * 64 + ((m) & 3) * 16 + lr;                                       \
        _Pragma("unroll")                                                                   \
        for (int ks = 0; ks < 2; ++ks)                                                      \
            dst[ks] = *(const i32x4*)&As[BUF][(m) >> 2][ra][(ks * 64 + lk16) ^ ((ra & 7) << 4)]; \
    }

#define DS_READ_B(BUF)                                                                      \
    {                                                                                       \
        _Pragma("unroll")                                                                   \
        for (int n = 0; n < 4; ++n) {                                                       \
            const int rb = (wn & 1) * 64 + n * 16 + lr;                                     \
            _Pragma("unroll")                                                               \
            for (int ks = 0; ks < 2; ++ks)                                                  \
                bv[n][ks] = *(const i32x4*)&Bs[BUF][wn >> 1][rb][(ks * 64 + lk16) ^ ((rb & 7) << 4)]; \
        }                                                                                   \
    }

#define MFMA_PH(mb, AV)                                                                     \
    do {                                                                                    \
        __builtin_amdgcn_s_setprio(1);                                                      \
        _Pragma("unroll")                                                                   \
        for (int mi = 0; mi < 2; ++mi)                                                      \
            _Pragma("unroll")                                                               \
            for (int n = 0; n < 4; ++n)                                                     \
                _Pragma("unroll")                                                           \
                for (int ks = 0; ks < 2; ++ks)                                              \
                    acc[(mb) + mi][n] = __builtin_amdgcn_mfma_i32_16x16x64_i8(              \
                        AV[mi][ks], bv[n][ks], acc[(mb) + mi][n], 0, 0, 0);                 \
        __builtin_amdgcn_s_setprio(0);                                                      \
    } while (0)

__global__ __launch_bounds__(512, 2) void kgemm(const u8* __restrict__ A,
                                                const u8* __restrict__ B,
                                                float* __restrict__ C,
                                                int M, int N, int K) {
    __shared__ u8 As[2][2][128][128];
    __shared__ u8 Bs[2][2][128][128];

    const int tid = threadIdx.x;
    const int lane = tid & 63;
    const int wid = tid >> 6;      // 0..7
    const int wm = wid >> 2;       // 0..1  (M sub-block within each half)
    const int wn = wid & 3;        // 0..3  (N sub-block)

    // T1: XCD-aware block swizzle (grid % 8 == 0 here)
    int bid = blockIdx.x;
    const int nwg = gridDim.x;
    if ((nwg & 7) == 0) bid = (bid & 7) * (nwg >> 3) + (bid >> 3);
    const int nbn = N >> 8;
    const int bm = bid / nbn, bn = bid % nbn;
    const int row0 = bm << 8, col0 = bn << 8;

    const int lr = lane & 15;
    const int lk16 = (lane >> 4) * 16;   // byte offset of this lane-group's K-chunk

    // staging thread mapping: 512 threads cover 64 rows x 128 bytes per load instr
    const int srow = tid >> 3;           // 0..63
    const int sec  = (tid & 7) * 16;     // 16-byte chunk within the 128B row

    i32x4 acc[8][4] = {};
    const int NT = K >> 7;               // 16 tiles of K=128 (K % 256 == 0 guaranteed)

    // ---- prologue: tile0 (4 halves) + tile1 (3 halves); certify tile0; preload ph1 frags
    STAGE_HALF(B, Bs[0][0], col0, 0);
    STAGE_HALF(B, Bs[0][1], col0 + 128, 0);
    STAGE_HALF(A, As[0][0], row0, 0);
    STAGE_HALF(A, As[0][1], row0 + 128, 0);
    STAGE_HALF(B, Bs[1][0], col0, 128);
    STAGE_HALF(B, Bs[1][1], col0 + 128, 128);
    STAGE_HALF(A, As[1][0], row0, 128);
    VMC6;
    BARRIER;

    i32x4 bv[4][2], av0[2][2], av1[2][2];
    DS_READ_B(0);
    DS_READ_A(0, 0, av0[0]); DS_READ_A(0, 1, av0[1]);

    for (int t = 0; t < NT; t += 2) {
        const int kb1 = (t + 1) << 7;
        const int kb2 = (t + 2 < NT ? t + 2 : NT - 1) << 7;   // clamped tail: dead-region
        const int kb3 = (t + 3 < NT ? t + 3 : NT - 1) << 7;   // re-stage, ledger exact

        // ph1: MFMA m0-1 (tile t); read m2-3
        STAGE_HALF(A, As[1][1], row0 + 128, kb1);
        BARRIER; LGKM0;
        MFMA_PH(0, av0);
        DS_READ_A(0, 2, av1[0]); DS_READ_A(0, 3, av1[1]);
        // ph2: MFMA m2-3; read m4-5
        STAGE_HALF(B, Bs[0][0], col0, kb2);
        BARRIER; LGKM0;
        MFMA_PH(2, av1);
        DS_READ_A(0, 4, av0[0]); DS_READ_A(0, 5, av0[1]);
        // ph3: MFMA m4-5; read m6-7
        STAGE_HALF(B, Bs[0][1], col0 + 128, kb2);
        BARRIER; LGKM0;
        MFMA_PH(4, av0);
        DS_READ_A(0, 6, av1[0]); DS_READ_A(0, 7, av1[1]);
        // ph4: certify tile t+1; MFMA m6-7; read tile t+1 B + m0-1
        STAGE_HALF(A, As[0][0], row0, kb2);
        VMC6;
        BARRIER; LGKM0;
        MFMA_PH(6, av1);
        DS_READ_B(1);
        DS_READ_A(1, 0, av0[0]); DS_READ_A(1, 1, av0[1]);
        // ph5: MFMA m0-1 (tile t+1); read m2-3
        STAGE_HALF(A, As[0][1], row0 + 128, kb2);
        BARRIER; LGKM0;
        MFMA_PH(0, av0);
        DS_READ_A(1, 2, av1[0]); DS_READ_A(1, 3, av1[1]);
        // ph6: MFMA m2-3; read m4-5
        STAGE_HALF(B, Bs[1][0], col0, kb3);
        BARRIER; LGKM0;
        MFMA_PH(2, av1);
        DS_READ_A(1, 4, av0[0]); DS_READ_A(1, 5, av0[1]);
        // ph7: MFMA m4-5; read m6-7
        STAGE_HALF(B, Bs[1][1], col0 + 128, kb3);
        BARRIER; LGKM0;
        MFMA_PH(4, av0);
        DS_READ_A(1, 6, av1[0]); DS_READ_A(1, 7, av1[1]);
        // ph8: certify tile t+2; MFMA m6-7; read tile t+2 B + m0-1
        STAGE_HALF(A, As[1][0], row0, kb3);
        VMC6;
        BARRIER; LGKM0;
        MFMA_PH(6, av1);
        DS_READ_B(0);
        DS_READ_A(0, 0, av0[0]); DS_READ_A(0, 1, av0[1]);
    }
    asm volatile("s_waitcnt vmcnt(0) lgkmcnt(0)" ::: "memory");

    // ---- epilogue: C/D layout col = lane&15, row = (lane>>4)*4 + reg (shape-determined,
    //      dtype-independent incl. i8 — m127/m128). i32 -> f32 exact (|acc| <= 2048).
#pragma unroll
    for (int m = 0; m < 8; ++m) {
        const int grow = row0 + (m >> 2) * 128 + wm * 64 + (m & 3) * 16 + (lane >> 4) * 4;
#pragma unroll
        for (int n = 0; n < 4; ++n) {
            float* cp = C + (size_t)grow * N + col0 + wn * 64 + n * 16 + (lane & 15);
#pragma unroll
            for (int r = 0; r < 4; ++r)
                cp[(size_t)r * N] = (float)acc[m][n][r];
        }
    }
}

// ---------------- correct-but-slow fallback if workspace is tiny ----------------

__global__ void knaive(const float* __restrict__ X, const float* __restrict__ W,
                       const float* __restrict__ gptr, float* __restrict__ out,
                       int N, int K) {
    size_t idx = (size_t)blockIdx.x * blockDim.x + threadIdx.x;
    const int m = (int)(idx / N), n = (int)(idx % N);
    const float g = *gptr;
    const float* xr = X + (size_t)m * K;
    const float* wrow = W + (size_t)n * K;
    float acc = 0.f;
    for (int k = 0; k < K; ++k) {
        float xv = xr[k];
        float xs = (xv > 0.f) ? 1.f : ((xv < 0.f) ? -1.f : 0.f);
        float w = wrow[k];
        float wq = (rintf(fabsf(w) / g) >= 1.f) ? ((w < 0.f) ? -1.f : 1.f) : 0.f;
        acc += xs * wq;
    }
    out[idx] = acc;
}

// ---------------- launch ----------------

extern "C" void kernel_launch(void* const* d_in, const int* in_sizes, int n_in,
                              void* d_out, int out_size, void* d_ws, size_t ws_size,
                              hipStream_t stream) {
    const float* x = (const float*)d_in[0];
    const float* W = (const float*)d_in[1];
    float* out = (float*)d_out;

    const int K = 2048;                 // in_features
    const int N = in_sizes[1] / K;      // out_features = 2048
    const int M = in_sizes[0] / K;      // 4*4096 = 16384
    const int nW = in_sizes[1];

    char* ws = (char*)d_ws;
    double* partials = (double*)ws;                       // 1024 doubles = 8 KB
    float* gamma = (float*)(ws + 8192);
    u8* wq = (u8*)(ws + 16384);
    u8* xq = (u8*)(ws + 16384 + (size_t)N * K);
    const size_t need = 16384 + (size_t)N * K + (size_t)M * K;

    kabs_partial<<<1024, 256, 0, stream>>>(W, partials, nW);
    kgamma<<<1, 256, 0, stream>>>(partials, gamma, nW);

    if (ws_size >= need && (M % 256) == 0 && (N % 256) == 0 && (K % 256) == 0) {
        kquant_w<<<nW / (256 * 4), 256, 0, stream>>>((const float4*)W, (unsigned int*)wq,
                                                     gamma, nW / 4);
        const size_t n16 = (size_t)M * K / 16;
        kquant_x<<<(unsigned)((n16 + 255) / 256), 256, 0, stream>>>(
            (const float4*)x, (uint4*)xq, n16);
        kgemm<<<(M / 256) * (N / 256), 512, 0, stream>>>(xq, wq, out, M, N, K);
    } else {
        knaive<<<(unsigned)((size_t)M * N / 256), 256, 0, stream>>>(x, W, gamma, out, N, K);
    }
}